// Round 9
// baseline (137.770 us; speedup 1.0000x reference)
//
#include <hip/hip_runtime.h>

// ---------------- problem constants ----------------
// N=512 nodes/heads, F_IN=256, H=64, C=64, K=12, ALPHA=0.2
// d_out: adj (512x512) followed by out (512x64), float32

// ---------------- ws float offsets ----------------
#define CAND_OFF 0        // 512*12 float2 = 12288 floats
#define KTH_OFF  12288    // 1 (pad 64)
#define INT_OFF  12352    // 64 int slots (header)
#define W2_OFF   12416    // 512*256 : w2[h][f]
#define E1_OFF   143488   // 512*16  : e1[h][r]
#define WH_OFF   151680   // 512*768 : Wh@entries per head
#define E2P_OFF  544896   // 4*512*512 : E2 f-quarter partials [q][h][j]
#define MIDC_OFF 1593472  // 12*32768 : compact mid rows
#define PART_OFF 1986688  // 128*768  : Wh2 partials [block][o]

// header int indices
#define H_M      0
#define H_R      1
#define H_ROWS   2
#define H_ER     14
#define H_EJ     26
#define H_ECJ    38

__device__ __forceinline__ float leaky_(float x) { return fmaxf(x, 0.2f * x); }
__device__ __forceinline__ float elu_(float x)   { return x > 0.f ? x : __expf(x) - 1.f; }

// K0a: A row b = V[b]·V^T -> d_out (raw), per-row top-12 candidates, zero out-sec.
__global__ __launch_bounds__(256) void k0a_adjA(const float* __restrict__ V,
                                                float* __restrict__ wsf,
                                                float* __restrict__ out) {
  __shared__ float vi[64];
  __shared__ float wv[48]; __shared__ int wi[48];
  int b = blockIdx.x, t = threadIdx.x, l = t & 63, w = t >> 6;
  if (t < 64) vi[t] = V[b * 64 + t];
  __syncthreads();
  float vr0, vr1;
  {
    const float4* vj = reinterpret_cast<const float4*>(V + t * 64);
    float acc = 0.f;
    #pragma unroll
    for (int q = 0; q < 16; ++q) {
      float4 v4 = vj[q];
      acc += v4.x * vi[q*4] + v4.y * vi[q*4+1] + v4.z * vi[q*4+2] + v4.w * vi[q*4+3];
    }
    vr0 = acc;
  }
  {
    const float4* vj = reinterpret_cast<const float4*>(V + (t + 256) * 64);
    float acc = 0.f;
    #pragma unroll
    for (int q = 0; q < 16; ++q) {
      float4 v4 = vj[q];
      acc += v4.x * vi[q*4] + v4.y * vi[q*4+1] + v4.z * vi[q*4+2] + v4.w * vi[q*4+3];
    }
    vr1 = acc;
  }
  out[b * 512 + t]       = vr0;
  out[b * 512 + 256 + t] = vr1;
  if (b < 128) out[262144 + b * 256 + t] = 0.f;

  // wave-local top-12 (no barriers inside rounds)
  float v0 = vr0, v1 = vr1;
  int j0 = t, j1 = t + 256;
  for (int round = 0; round < 12; ++round) {
    float m; int mi;
    if (v0 >= v1) { m = v0; mi = j0; } else { m = v1; mi = j1; }
    #pragma unroll
    for (int d = 1; d < 64; d <<= 1) {
      float ov = __shfl_xor(m, d);
      int   oi = __shfl_xor(mi, d);
      if (ov > m || (ov == m && oi < mi)) { m = ov; mi = oi; }
    }
    if (l == 0) { wv[w * 12 + round] = m; wi[w * 12 + round] = mi; }
    if (mi == j0) v0 = -INFINITY;
    if (mi == j1) v1 = -INFINITY;
  }
  __syncthreads();
  if (w == 0) {
    float cv = (l < 48) ? wv[l] : -INFINITY;
    int   ci = (l < 48) ? wi[l] : 0x7FFFFFFF;
    for (int round = 0; round < 12; ++round) {
      float m = cv; int mi = ci;
      #pragma unroll
      for (int d = 1; d < 64; d <<= 1) {
        float ov = __shfl_xor(m, d);
        int   oi = __shfl_xor(mi, d);
        if (ov > m || (ov == m && oi < mi)) { m = ov; mi = oi; }
      }
      if (l == 0) {
        float2 c; c.x = m; c.y = __int_as_float(b * 512 + mi);
        *reinterpret_cast<float2*>(wsf + CAND_OFF + (b * 12 + round) * 2) = c;
      }
      if (ci == mi) cv = -INFINITY;
    }
  }
}

// K0b: single block: 6144 candidates -> kth + header (register-resident, ballot)
__global__ void k0b_header(float* __restrict__ wsf) {
  __shared__ float redv[4]; __shared__ int redi[4];
  __shared__ float candv[12]; __shared__ int candi[12];
  __shared__ int es_s[12], rows_s[12];
  __shared__ int M_s, R_s;
  int t = threadIdx.x, l = t & 63, w = t >> 6;

  float v[24]; int ix[24];
  const float2* cp = reinterpret_cast<const float2*>(wsf + CAND_OFF);
  #pragma unroll
  for (int k = 0; k < 24; ++k) {
    float2 c = cp[k * 256 + t];
    v[k] = c.x; ix[k] = __float_as_int(c.y);
  }
  unsigned rm = 0;
  for (int round = 0; round < 12; ++round) {
    float m = -INFINITY; int mi = 0x7FFFFFFF; int sel = -1;
    #pragma unroll
    for (int k = 0; k < 24; ++k) {
      bool ok = ((rm >> k) & 1u) == 0u;
      bool better = ok && (v[k] > m || (v[k] == m && ix[k] < mi));
      if (better) { m = v[k]; mi = ix[k]; sel = k; }
    }
    int lmi = mi;
    #pragma unroll
    for (int d = 1; d < 64; d <<= 1) {
      float ov = __shfl_xor(m, d);
      int   oi = __shfl_xor(mi, d);
      if (ov > m || (ov == m && oi < mi)) { m = ov; mi = oi; }
    }
    if (l == 0) { redv[w] = m; redi[w] = mi; }
    __syncthreads();
    float bm = redv[0]; int bi = redi[0];
    #pragma unroll
    for (int ww = 1; ww < 4; ++ww)
      if (redv[ww] > bm || (redv[ww] == bm && redi[ww] < bi)) { bm = redv[ww]; bi = redi[ww]; }
    if (t == 0) { candv[round] = bm; candi[round] = bi; }
    if (sel >= 0 && lmi == bi) rm |= 1u << sel;
    __syncthreads();
  }
  float kv = candv[11];
  bool valid = (t < 12) && (candv[t] > kv);
  int myidx = valid ? candi[t] : 0x7FFFFFFF;
  unsigned long long vm = __ballot(valid);
  if (t < 12) {
    int rank = 0;
    #pragma unroll
    for (int q = 0; q < 12; ++q)
      if (((vm >> q) & 1ull) && candi[q] < myidx) ++rank;
    if (valid) es_s[rank] = myidx;
    if (t == 0) M_s = (int)__popcll(vm & 0xFFFull);
  }
  __syncthreads();
  int M = M_s;
  bool isent = (t < M);
  int i2 = isent ? (es_s[t] >> 9) : -1;
  int j2 = isent ? (es_s[t] & 511) : 0;
  bool isnew = isent && (t == 0 || (es_s[t - 1] >> 9) != i2);
  unsigned long long nm = __ballot(isnew);
  if (isnew) {
    int r = (int)__popcll(nm & ((1ull << t) - 1ull));
    rows_s[r] = i2;
  }
  if (t == 0) R_s = (int)__popcll(nm & 0xFFFull);
  __syncthreads();
  int R = R_s;
  int* ip = (int*)(wsf + INT_OFF);
  if (t == 0) { ip[H_M] = M; ip[H_R] = R; wsf[KTH_OFF] = kv; }
  if (t < 12) {
    ip[H_ROWS + t] = (t < R) ? rows_s[t] : 0;
    int er = 0, ecj = -1;
    if (isent) {
      er = (int)__popcll(nm & ((2ull << t) - 1ull)) - 1;
      for (int r = 0; r < R; ++r) if (rows_s[r] == j2) ecj = r;
    }
    ip[H_ER + t]  = er;
    ip[H_EJ + t]  = isent ? j2 : 0;
    ip[H_ECJ + t] = ecj;
  }
}

// K1: one block per head h=b. THE single W_stack pass: adj row write; w1/w2
// (deferred 16-lane reduce), Wh@entries (f-partials), e1. W read exactly once.
__global__ __launch_bounds__(256) void k1_wpass(
    const float* __restrict__ X, const float* __restrict__ Wst,
    const float* __restrict__ ast, float* __restrict__ wsf,
    float* __restrict__ out) {
  __shared__ int   shdr[64];
  __shared__ float w1l[256], w2l[256];
  __shared__ __align__(16) float XeT[3072];   // [f][m]
  __shared__ __align__(16) float whp[3072];
  int b = blockIdx.x, t = threadIdx.x, l = t & 63, w = t >> 6;
  const int* ip = (const int*)(wsf + INT_OFF);

  // adj row write (raw A -> 0/1), using kth from k0b
  {
    float kv = wsf[KTH_OFF];
    float a0 = out[b * 512 + t], a1 = out[b * 512 + 256 + t];
    out[b * 512 + t]       = (a0 > kv) ? 1.f : 0.f;
    out[b * 512 + 256 + t] = (a1 > kv) ? 1.f : 0.f;
  }
  if (t < 50) shdr[t] = ip[t];
  __syncthreads();
  int M = shdr[H_M], R = shdr[H_R];

  #pragma unroll
  for (int m = 0; m < 12; ++m) {
    float v = 0.f;
    if (m < M) v = X[shdr[H_EJ + m] * 256 + t];
    XeT[t * 12 + m] = v;
  }
  __syncthreads();

  const float* Wb = Wst + b * 16384;
  int fg = l >> 4, kc = (l & 15) << 2;
  float4 a1q = *reinterpret_cast<const float4*>(ast + b * 128 + kc);
  float4 a2q = *reinterpret_cast<const float4*>(ast + b * 128 + 64 + kc);
  float wh[12][4];
  float p1a[16], p2a[16];
  #pragma unroll
  for (int m = 0; m < 12; ++m) { wh[m][0] = wh[m][1] = wh[m][2] = wh[m][3] = 0.f; }

  // hot loop: pure load + FMA (no cross-lane ops)
  #pragma unroll 4
  for (int it = 0; it < 16; ++it) {
    int f = w * 64 + it * 4 + fg;
    float4 wq = *reinterpret_cast<const float4*>(Wb + f * 64 + kc);
    p1a[it] = wq.x*a1q.x + wq.y*a1q.y + wq.z*a1q.z + wq.w*a1q.w;
    p2a[it] = wq.x*a2q.x + wq.y*a2q.y + wq.z*a2q.z + wq.w*a2q.w;
    const float4* xr = reinterpret_cast<const float4*>(&XeT[f * 12]);
    float4 xa = xr[0], xb = xr[1], xc = xr[2];
    float xv[12] = { xa.x, xa.y, xa.z, xa.w, xb.x, xb.y, xb.z, xb.w,
                     xc.x, xc.y, xc.z, xc.w };
    #pragma unroll
    for (int m = 0; m < 12; ++m) {
      wh[m][0] += xv[m] * wq.x;
      wh[m][1] += xv[m] * wq.y;
      wh[m][2] += xv[m] * wq.z;
      wh[m][3] += xv[m] * wq.w;
    }
  }
  // deferred w1/w2 reduction (16-lane groups share f)
  #pragma unroll
  for (int it = 0; it < 16; ++it) {
    float p1 = p1a[it], p2 = p2a[it];
    #pragma unroll
    for (int d = 1; d < 16; d <<= 1) { p1 += __shfl_xor(p1, d); p2 += __shfl_xor(p2, d); }
    if ((l & 15) == 0) {
      int f = w * 64 + it * 4 + fg;
      w1l[f] = p1; w2l[f] = p2;
    }
  }
  // Wh reduce over the 4 f-groups in the wave
  #pragma unroll
  for (int m = 0; m < 12; ++m) {
    #pragma unroll
    for (int q = 0; q < 4; ++q) {
      float x = wh[m][q];
      x += __shfl_xor(x, 16);
      x += __shfl_xor(x, 32);
      wh[m][q] = x;
    }
  }
  if (l < 16) {
    #pragma unroll
    for (int m = 0; m < 12; ++m) {
      float4 vv = make_float4(wh[m][0], wh[m][1], wh[m][2], wh[m][3]);
      *reinterpret_cast<float4*>(&whp[w * 768 + m * 64 + kc]) = vv;
    }
  }
  __syncthreads();
  // cross-wave Wh reduce -> ws; w2 -> ws (for E2 GEMM)
  #pragma unroll
  for (int c = 0; c < 3; ++c) {
    int o = c * 256 + t;
    wsf[WH_OFF + b * 768 + o] = whp[o] + whp[768 + o] + whp[1536 + o] + whp[2304 + o];
  }
  wsf[W2_OFF + b * 256 + t] = w2l[t];
  // e1 at adjacency rows
  for (int r = w; r < R; r += 4) {
    int row = shdr[H_ROWS + r];
    float p = 0.f;
    #pragma unroll
    for (int s = 0; s < 4; ++s) {
      int f = s * 64 + l;
      p += X[row * 256 + f] * w1l[f];
    }
    #pragma unroll
    for (int d = 1; d < 64; d <<= 1) p += __shfl_xor(p, d);
    if (l == 0) wsf[E1_OFF + b * 16 + r] = p;
  }
}

// K2: E2 f-quarter-partial GEMM: E2[h][j] = sum_f w2[h][f] * X[j][f]
__global__ __launch_bounds__(256) void k2_e2(const float* __restrict__ X,
                                             float* __restrict__ wsf) {
  __shared__ __align__(16) float As[64][68];
  __shared__ __align__(16) float Bs[64][68];
  int b = blockIdx.x, t = threadIdx.x;
  int q = b >> 6, bh = (b >> 3) & 7, bj = b & 7;
  int r = t >> 2, c0 = (t & 3) * 16;
  const float* wsrc = wsf + W2_OFF + (bh * 64 + r) * 256 + q * 64 + c0;
  const float* xsrc = X + (bj * 64 + r) * 256 + q * 64 + c0;
  #pragma unroll
  for (int u = 0; u < 4; ++u) {
    float4 a4 = *reinterpret_cast<const float4*>(wsrc + u * 4);
    float4 b4 = *reinterpret_cast<const float4*>(xsrc + u * 4);
    As[c0 + u*4 + 0][r] = a4.x; As[c0 + u*4 + 1][r] = a4.y;
    As[c0 + u*4 + 2][r] = a4.z; As[c0 + u*4 + 3][r] = a4.w;
    Bs[c0 + u*4 + 0][r] = b4.x; Bs[c0 + u*4 + 1][r] = b4.y;
    Bs[c0 + u*4 + 2][r] = b4.z; Bs[c0 + u*4 + 3][r] = b4.w;
  }
  __syncthreads();
  int th = t >> 4, tj = t & 15;
  float acc[4][4] = {};
  #pragma unroll 8
  for (int f = 0; f < 64; ++f) {
    float4 a4 = *reinterpret_cast<const float4*>(&As[f][th * 4]);
    float4 b4 = *reinterpret_cast<const float4*>(&Bs[f][tj * 4]);
    float av[4] = { a4.x, a4.y, a4.z, a4.w };
    float bv[4] = { b4.x, b4.y, b4.z, b4.w };
    #pragma unroll
    for (int i = 0; i < 4; ++i)
      #pragma unroll
      for (int j = 0; j < 4; ++j)
        acc[i][j] += av[i] * bv[j];
  }
  float* dst = wsf + E2P_OFF + q * 262144 + (bh * 64 + th * 4) * 512 + bj * 64 + tj * 4;
  #pragma unroll
  for (int i = 0; i < 4; ++i) {
    float4 o4 = make_float4(acc[i][0], acc[i][1], acc[i][2], acc[i][3]);
    *reinterpret_cast<float4*>(dst + i * 512) = o4;
  }
}

// K3: per head: merge E2 quarters, softmax stats, avals, mid accumulate
__global__ __launch_bounds__(256) void k3_stats(float* __restrict__ wsf) {
  __shared__ int   shdr[64];
  __shared__ float e1r[12], whl[768], e2s[512];
  __shared__ float redv[4], redf[48], mr12[12], sr12[12], av12[12];
  int b = blockIdx.x, t = threadIdx.x, l = t & 63, w = t >> 6;
  const int* ip = (const int*)(wsf + INT_OFF);
  if (t < 50) shdr[t] = ip[t];
  if (t >= 128 && t < 140) e1r[t - 128] = wsf[E1_OFF + b * 16 + (t - 128)];
  #pragma unroll
  for (int c = 0; c < 3; ++c) {
    int o = c * 256 + t;
    whl[o] = wsf[WH_OFF + b * 768 + o];
  }
  {
    float s0 = 0.f, s1 = 0.f;
    #pragma unroll
    for (int qq = 0; qq < 4; ++qq) {
      s0 += wsf[E2P_OFF + qq * 262144 + b * 512 + t];
      s1 += wsf[E2P_OFF + qq * 262144 + b * 512 + 256 + t];
    }
    e2s[t] = s0; e2s[t + 256] = s1;
  }
  __syncthreads();
  int M = shdr[H_M], R = shdr[H_R];
  {
    float p = fmaxf(e2s[w * 128 + l], e2s[w * 128 + 64 + l]);
    #pragma unroll
    for (int d = 1; d < 64; d <<= 1) p = fmaxf(p, __shfl_xor(p, d));
    if (l == 0) redv[w] = p;
  }
  __syncthreads();
  float maxe2 = fmaxf(fmaxf(redv[0], redv[1]), fmaxf(redv[2], redv[3]));
  for (int r = 0; r < R; ++r) {
    float e1_ = e1r[r];
    float m_ = leaky_(e1_ + maxe2);
    float pe = __expf(leaky_(e1_ + e2s[t]) - m_) + __expf(leaky_(e1_ + e2s[t + 256]) - m_);
    #pragma unroll
    for (int d = 1; d < 64; d <<= 1) pe += __shfl_xor(pe, d);
    if (l == 0) redf[r * 4 + w] = pe;
    if (t == r) mr12[r] = m_;
  }
  __syncthreads();
  if (t < R) sr12[t] = redf[t * 4] + redf[t * 4 + 1] + redf[t * 4 + 2] + redf[t * 4 + 3];
  __syncthreads();
  if (t < M) {
    int r = shdr[H_ER + t];
    av12[t] = __expf(leaky_(e1r[r] + e2s[shdr[H_EJ + t]]) - mr12[r]) / sr12[r];
  }
  __syncthreads();
  for (int r = w; r < R; r += 4) {
    float a = 0.f;
    #pragma unroll
    for (int m = 0; m < 12; ++m) {
      if (m < M && shdr[H_ER + m] == r) a += av12[m] * whl[m * 64 + l];
    }
    wsf[MIDC_OFF + r * 32768 + b * 64 + l] = elu_(a);
  }
}

// K4: Wh2 partials: block b covers mid columns [b*256, b*256+256)
__global__ __launch_bounds__(256) void k4_wh2(const float* __restrict__ Wout,
                                              float* __restrict__ wsf) {
  __shared__ __align__(16) float midT[3072];
  __shared__ float whp4[4][768];
  int b = blockIdx.x, t = threadIdx.x, l = t & 63, w = t >> 6;
  const int* ip = (const int*)(wsf + INT_OFF);
  int R = ip[H_R];

  #pragma unroll
  for (int m = 0; m < 12; ++m) {
    float v = 0.f;
    if (m < R) v = wsf[MIDC_OFF + m * 32768 + b * 256 + t];
    midT[t * 12 + m] = v;
  }
  __syncthreads();
  float acc[12];
  #pragma unroll
  for (int m = 0; m < 12; ++m) acc[m] = 0.f;
  #pragma unroll 2
  for (int ci = 0; ci < 64; ++ci) {
    int cc = w * 64 + ci;
    float wv = Wout[(b * 256 + cc) * 64 + l];
    const float4* xr = reinterpret_cast<const float4*>(&midT[cc * 12]);
    float4 xa = xr[0], xb = xr[1], xc = xr[2];
    acc[0] += xa.x * wv; acc[1] += xa.y * wv; acc[2]  += xa.z * wv; acc[3]  += xa.w * wv;
    acc[4] += xb.x * wv; acc[5] += xb.y * wv; acc[6]  += xb.z * wv; acc[7]  += xb.w * wv;
    acc[8] += xc.x * wv; acc[9] += xc.y * wv; acc[10] += xc.z * wv; acc[11] += xc.w * wv;
  }
  #pragma unroll
  for (int m = 0; m < 12; ++m) whp4[w][m * 64 + l] = acc[m];
  __syncthreads();
  #pragma unroll
  for (int c = 0; c < 3; ++c) {
    int o = c * 256 + t;
    float s = whp4[0][o] + whp4[1][o] + whp4[2][o] + whp4[3][o];
    wsf[PART_OFF + b * 768 + o] = s;
  }
}

// K5: reduce Wh2 partials; layer-2 closed-form softmax; final elu(V*elu(out2))
__global__ void k5_final(const float* __restrict__ aout, const float* __restrict__ V,
                         float* __restrict__ wsf, float* __restrict__ out) {
  __shared__ float Wh2[768];
  __shared__ float e1o[12], e2o[12], mr[12], sr[12], avals[12];
  int t = threadIdx.x;
  const int* ip = (const int*)(wsf + INT_OFF);
  int M = ip[H_M], R = ip[H_R];
  for (int o = t, c = 0; c < 3; ++c, o += 256) {
    float s = 0.f;
    #pragma unroll 8
    for (int bb = 0; bb < 128; ++bb) s += wsf[PART_OFF + bb * 768 + o];
    Wh2[o] = s;
  }
  __syncthreads();
  if (t < R) {
    float s1 = 0.f, s2 = 0.f;
    for (int k = 0; k < 64; ++k) {
      float wv = Wh2[t * 64 + k];
      s1 += wv * aout[k];
      s2 += wv * aout[64 + k];
    }
    e1o[t] = s1; e2o[t] = s2;
  }
  __syncthreads();
  if (t < R) {
    float maxe = 0.f;  // includes (512-R) implicit zeros
    for (int r = 0; r < R; ++r) maxe = fmaxf(maxe, e2o[r]);
    float m_ = leaky_(e1o[t] + maxe);
    float s = (float)(512 - R) * __expf(leaky_(e1o[t]) - m_);
    for (int r = 0; r < R; ++r) s += __expf(leaky_(e1o[t] + e2o[r]) - m_);
    mr[t] = m_; sr[t] = s;
  }
  __syncthreads();
  if (t < M) {
    int r = ip[H_ER + t];
    int cj = ip[H_ECJ + t];
    float e2v = (cj >= 0) ? e2o[cj] : 0.f;
    avals[t] = __expf(leaky_(e1o[r] + e2v) - mr[r]) / sr[r];
  }
  __syncthreads();
  int l = t & 63, w = t >> 6;
  for (int r = w; r < R; r += 4) {
    float a = 0.f;
    #pragma unroll
    for (int m = 0; m < 12; ++m) {
      if (m < M && ip[H_ER + m] == r) {
        int cj = ip[H_ECJ + m];
        float wv = (cj >= 0) ? Wh2[cj * 64 + l] : 0.f;
        a += avals[m] * wv;
      }
    }
    int row = ip[H_ROWS + r];
    float o2 = elu_(a);
    out[262144 + row * 64 + l] = elu_(V[row * 64 + l] * o2);
  }
}

extern "C" void kernel_launch(void* const* d_in, const int* in_sizes, int n_in,
                              void* d_out, int out_size, void* d_ws, size_t ws_size,
                              hipStream_t stream) {
  const float* X    = (const float*)d_in[0];
  const float* Wst  = (const float*)d_in[1];
  const float* ast  = (const float*)d_in[2];
  const float* Wout = (const float*)d_in[3];
  const float* aout = (const float*)d_in[4];
  const float* V    = (const float*)d_in[5];
  float* out = (float*)d_out;
  float* wsf = (float*)d_ws;

  k0a_adjA <<<512, 256, 0, stream>>>(V, wsf, out);
  k0b_header<<<1,  256, 0, stream>>>(wsf);
  k1_wpass <<<512, 256, 0, stream>>>(X, Wst, ast, wsf, out);
  k2_e2    <<<256, 256, 0, stream>>>(X, wsf);
  k3_stats <<<512, 256, 0, stream>>>(wsf);
  k4_wh2   <<<128, 256, 0, stream>>>(Wout, wsf);
  k5_final <<<1,   256, 0, stream>>>(aout, V, wsf, out);
}

// Round 10
// 130.353 us; speedup vs baseline: 1.0569x; 1.0569x over previous
//
#include <hip/hip_runtime.h>

// ---------------- problem constants ----------------
// N=512 nodes/heads, F_IN=256, H=64, C=64, K=12, ALPHA=0.2
// d_out: adj (512x512) followed by out (512x64), float32
//
// Structure = round-8 empirical optimum (132.8 us), dead code removed:
//  k1 (1024 blk): A=VV^T rows + per-row top-12 cands + w1/w2 = W_h^T a  (parallel halves)
//  k2 (257 blk):  E2 = W2 · X^T quarter-partial GEMM  +  header block
//  k3 (512 blk):  per-head: adj row, Wh@entry-cols (W from L3), e1, E2 merge, softmax, mid
//  k4 (128 blk):  Wh2 partials over mid columns (W_out read once)
//  k5 (1 blk):    partial reduce + layer-2 closed-form softmax + elu(V*elu(out2))

// ---------------- ws float offsets ----------------
#define CAND_OFF 0        // 512*12 float2 = 12288 floats
#define KTH_OFF  12288    // 1 (pad 64)
#define INT_OFF  12352    // 64 int slots (header)
#define W1_OFF   12416    // 512*256 : w1[h][f]
#define W2_OFF   143488   // 512*256 : w2[h][f]
#define E2P_OFF  274560   // 4*512*512 : E2 f-quarter partials [q][h][j]
#define MIDC_OFF 1323136  // 12*32768 : compact mid rows
#define PART_OFF 1716352  // 128*768  : Wh2 partials [block][o]

// header int indices
#define H_M      0
#define H_R      1
#define H_ROWS   2
#define H_ER     14
#define H_EJ     26
#define H_ECJ    38

__device__ __forceinline__ float leaky_(float x) { return fmaxf(x, 0.2f * x); }
__device__ __forceinline__ float elu_(float x)   { return x > 0.f ? x : __expf(x) - 1.f; }

// K1: blocks 0..511: A row b + per-row top-12 candidates + zero out-section.
//     blocks 512..1023: w1/w2 for head (b-512) — W_stack streamed, deferred reduce.
__global__ __launch_bounds__(256) void k1_prep(const float* __restrict__ V,
                                               const float* __restrict__ Wst,
                                               const float* __restrict__ ast,
                                               float* __restrict__ wsf,
                                               float* __restrict__ out) {
  __shared__ float vi[64];
  __shared__ float wv[48]; __shared__ int wi[48];
  int b = blockIdx.x, t = threadIdx.x, l = t & 63, w = t >> 6;

  if (b < 512) {
    if (t < 64) vi[t] = V[b * 64 + t];
    __syncthreads();
    float vr0, vr1;
    {
      const float4* vj = reinterpret_cast<const float4*>(V + t * 64);
      float acc = 0.f;
      #pragma unroll
      for (int q = 0; q < 16; ++q) {
        float4 v4 = vj[q];
        acc += v4.x * vi[q*4] + v4.y * vi[q*4+1] + v4.z * vi[q*4+2] + v4.w * vi[q*4+3];
      }
      vr0 = acc;
    }
    {
      const float4* vj = reinterpret_cast<const float4*>(V + (t + 256) * 64);
      float acc = 0.f;
      #pragma unroll
      for (int q = 0; q < 16; ++q) {
        float4 v4 = vj[q];
        acc += v4.x * vi[q*4] + v4.y * vi[q*4+1] + v4.z * vi[q*4+2] + v4.w * vi[q*4+3];
      }
      vr1 = acc;
    }
    out[b * 512 + t]       = vr0;
    out[b * 512 + 256 + t] = vr1;
    if (b < 128) out[262144 + b * 256 + t] = 0.f;

    // wave-local top-12 (no barriers inside rounds)
    float v0 = vr0, v1 = vr1;
    int j0 = t, j1 = t + 256;
    for (int round = 0; round < 12; ++round) {
      float m; int mi;
      if (v0 >= v1) { m = v0; mi = j0; } else { m = v1; mi = j1; }
      #pragma unroll
      for (int d = 1; d < 64; d <<= 1) {
        float ov = __shfl_xor(m, d);
        int   oi = __shfl_xor(mi, d);
        if (ov > m || (ov == m && oi < mi)) { m = ov; mi = oi; }
      }
      if (l == 0) { wv[w * 12 + round] = m; wi[w * 12 + round] = mi; }
      if (mi == j0) v0 = -INFINITY;
      if (mi == j1) v1 = -INFINITY;
    }
    __syncthreads();
    if (w == 0) {
      float cv = (l < 48) ? wv[l] : -INFINITY;
      int   ci = (l < 48) ? wi[l] : 0x7FFFFFFF;
      for (int round = 0; round < 12; ++round) {
        float m = cv; int mi = ci;
        #pragma unroll
        for (int d = 1; d < 64; d <<= 1) {
          float ov = __shfl_xor(m, d);
          int   oi = __shfl_xor(mi, d);
          if (ov > m || (ov == m && oi < mi)) { m = ov; mi = oi; }
        }
        if (l == 0) {
          float2 c; c.x = m; c.y = __int_as_float(b * 512 + mi);
          *reinterpret_cast<float2*>(wsf + CAND_OFF + (b * 12 + round) * 2) = c;
        }
        if (ci == mi) cv = -INFINITY;   // indices unique within block
      }
    }
  } else {
    // w1/w2 pass: head h, pure stream of W_h with deferred 16-lane reduction
    int h = b - 512;
    int kc = (t & 15) << 2;
    float4 a1q = *reinterpret_cast<const float4*>(ast + h * 128 + kc);
    float4 a2q = *reinterpret_cast<const float4*>(ast + h * 128 + 64 + kc);
    const float* Wb = Wst + h * 16384;
    float p1a[16], p2a[16];
    #pragma unroll
    for (int it = 0; it < 16; ++it) {
      float4 wq = *reinterpret_cast<const float4*>(Wb + it * 1024 + t * 4);
      p1a[it] = wq.x*a1q.x + wq.y*a1q.y + wq.z*a1q.z + wq.w*a1q.w;
      p2a[it] = wq.x*a2q.x + wq.y*a2q.y + wq.z*a2q.z + wq.w*a2q.w;
    }
    #pragma unroll
    for (int it = 0; it < 16; ++it) {
      float p1 = p1a[it], p2 = p2a[it];
      #pragma unroll
      for (int d = 1; d < 16; d <<= 1) { p1 += __shfl_xor(p1, d); p2 += __shfl_xor(p2, d); }
      if ((t & 15) == 0) {
        int f = it * 16 + (t >> 4);
        wsf[W1_OFF + h * 256 + f] = p1;
        wsf[W2_OFF + h * 256 + f] = p2;
      }
    }
  }
}

// K2: blocks 0..255: E2 f-quarter-partial GEMM (W2 · X^T).
//     block 256: header build from 6144 candidates (register-resident, ballot).
__global__ __launch_bounds__(256) void k2_e2hdr(const float* __restrict__ X,
                                                float* __restrict__ wsf) {
  __shared__ __align__(16) float As[64][68];
  __shared__ __align__(16) float Bs[64][68];
  __shared__ float redv[4]; __shared__ int redi[4];
  __shared__ float candv[12]; __shared__ int candi[12];
  __shared__ int es_s[12], rows_s[12];
  __shared__ int M_s, R_s;
  int b = blockIdx.x, t = threadIdx.x, l = t & 63, w = t >> 6;

  if (b < 256) {
    int q = b >> 6, bh = (b >> 3) & 7, bj = b & 7;
    int r = t >> 2, c0 = (t & 3) * 16;
    const float* wsrc = wsf + W2_OFF + (bh * 64 + r) * 256 + q * 64 + c0;
    const float* xsrc = X + (bj * 64 + r) * 256 + q * 64 + c0;
    #pragma unroll
    for (int u = 0; u < 4; ++u) {
      float4 a4 = *reinterpret_cast<const float4*>(wsrc + u * 4);
      float4 b4 = *reinterpret_cast<const float4*>(xsrc + u * 4);
      As[c0 + u*4 + 0][r] = a4.x; As[c0 + u*4 + 1][r] = a4.y;
      As[c0 + u*4 + 2][r] = a4.z; As[c0 + u*4 + 3][r] = a4.w;
      Bs[c0 + u*4 + 0][r] = b4.x; Bs[c0 + u*4 + 1][r] = b4.y;
      Bs[c0 + u*4 + 2][r] = b4.z; Bs[c0 + u*4 + 3][r] = b4.w;
    }
    __syncthreads();
    int th = t >> 4, tj = t & 15;
    float acc[4][4] = {};
    #pragma unroll 8
    for (int f = 0; f < 64; ++f) {
      float4 a4 = *reinterpret_cast<const float4*>(&As[f][th * 4]);
      float4 b4 = *reinterpret_cast<const float4*>(&Bs[f][tj * 4]);
      float av[4] = { a4.x, a4.y, a4.z, a4.w };
      float bv[4] = { b4.x, b4.y, b4.z, b4.w };
      #pragma unroll
      for (int i = 0; i < 4; ++i)
        #pragma unroll
        for (int j = 0; j < 4; ++j)
          acc[i][j] += av[i] * bv[j];
    }
    float* dst = wsf + E2P_OFF + q * 262144 + (bh * 64 + th * 4) * 512 + bj * 64 + tj * 4;
    #pragma unroll
    for (int i = 0; i < 4; ++i) {
      float4 o4 = make_float4(acc[i][0], acc[i][1], acc[i][2], acc[i][3]);
      *reinterpret_cast<float4*>(dst + i * 512) = o4;
    }
    return;
  }

  // ---- header block ----
  float v[24]; int ix[24];
  const float2* cp = reinterpret_cast<const float2*>(wsf + CAND_OFF);
  #pragma unroll
  for (int k = 0; k < 24; ++k) {
    float2 c = cp[k * 256 + t];
    v[k] = c.x; ix[k] = __float_as_int(c.y);
  }
  unsigned rm = 0;
  for (int round = 0; round < 12; ++round) {
    float m = -INFINITY; int mi = 0x7FFFFFFF; int sel = -1;
    #pragma unroll
    for (int k = 0; k < 24; ++k) {
      bool ok = ((rm >> k) & 1u) == 0u;
      bool better = ok && (v[k] > m || (v[k] == m && ix[k] < mi));
      if (better) { m = v[k]; mi = ix[k]; sel = k; }
    }
    int lmi = mi;
    #pragma unroll
    for (int d = 1; d < 64; d <<= 1) {
      float ov = __shfl_xor(m, d);
      int   oi = __shfl_xor(mi, d);
      if (ov > m || (ov == m && oi < mi)) { m = ov; mi = oi; }
    }
    if (l == 0) { redv[w] = m; redi[w] = mi; }
    __syncthreads();
    float bm = redv[0]; int bi = redi[0];
    #pragma unroll
    for (int ww = 1; ww < 4; ++ww)
      if (redv[ww] > bm || (redv[ww] == bm && redi[ww] < bi)) { bm = redv[ww]; bi = redi[ww]; }
    if (t == 0) { candv[round] = bm; candi[round] = bi; }
    if (sel >= 0 && lmi == bi) rm |= 1u << sel;
    __syncthreads();
  }
  float kv = candv[11];
  bool valid = (t < 12) && (candv[t] > kv);
  int myidx = valid ? candi[t] : 0x7FFFFFFF;
  unsigned long long vm = __ballot(valid);
  if (t < 12) {
    int rank = 0;
    #pragma unroll
    for (int q = 0; q < 12; ++q)
      if (((vm >> q) & 1ull) && candi[q] < myidx) ++rank;
    if (valid) es_s[rank] = myidx;
    if (t == 0) M_s = (int)__popcll(vm & 0xFFFull);
  }
  __syncthreads();
  int M = M_s;
  bool isent = (t < M);
  int i2 = isent ? (es_s[t] >> 9) : -1;
  int j2 = isent ? (es_s[t] & 511) : 0;
  bool isnew = isent && (t == 0 || (es_s[t - 1] >> 9) != i2);
  unsigned long long nm = __ballot(isnew);
  if (isnew) {
    int r = (int)__popcll(nm & ((1ull << t) - 1ull));
    rows_s[r] = i2;
  }
  if (t == 0) R_s = (int)__popcll(nm & 0xFFFull);
  __syncthreads();
  int R = R_s;
  int* ip = (int*)(wsf + INT_OFF);
  if (t == 0) { ip[H_M] = M; ip[H_R] = R; wsf[KTH_OFF] = kv; }
  if (t < 12) {
    ip[H_ROWS + t] = (t < R) ? rows_s[t] : 0;
    int er = 0, ecj = -1;
    if (isent) {
      er = (int)__popcll(nm & ((2ull << t) - 1ull)) - 1;
      for (int r = 0; r < R; ++r) if (rows_s[r] == j2) ecj = r;
    }
    ip[H_ER + t]  = er;
    ip[H_EJ + t]  = isent ? j2 : 0;
    ip[H_ECJ + t] = ecj;
  }
}

// K3: one block per head. adj row write; dense W pass (Wh@entries only, no
// cross-lane ops in hot loop, W from L3); e1 via precomputed w1; E2 merge;
// softmax stats; mid write.
__global__ __launch_bounds__(256) void k3_heads(
    const float* __restrict__ X, const float* __restrict__ Wst,
    float* __restrict__ wsf, float* __restrict__ out) {
  __shared__ int   shdr[64];
  __shared__ __align__(16) float XeT[3072];
  __shared__ __align__(16) float whp[3072];
  __shared__ float w1l[256];
  __shared__ float e2s[512];
  __shared__ float whl[768];
  __shared__ float e1r[12], mr12[12], sr12[12], av12[12];
  __shared__ float redv[4], redf[48];

  int b = blockIdx.x, t = threadIdx.x, l = t & 63, w = t >> 6;
  const int* ip = (const int*)(wsf + INT_OFF);

  // adj row write
  {
    float kv = wsf[KTH_OFF];
    float a0 = out[b * 512 + t], a1 = out[b * 512 + 256 + t];
    out[b * 512 + t]       = (a0 > kv) ? 1.f : 0.f;
    out[b * 512 + 256 + t] = (a1 > kv) ? 1.f : 0.f;
  }
  if (t < 50) shdr[t] = ip[t];
  w1l[t] = wsf[W1_OFF + b * 256 + t];
  {
    float s0 = 0.f, s1 = 0.f;
    #pragma unroll
    for (int q = 0; q < 4; ++q) {
      s0 += wsf[E2P_OFF + q * 262144 + b * 512 + t];
      s1 += wsf[E2P_OFF + q * 262144 + b * 512 + 256 + t];
    }
    e2s[t] = s0; e2s[t + 256] = s1;
  }
  __syncthreads();
  int M = shdr[H_M], R = shdr[H_R];

  #pragma unroll
  for (int m = 0; m < 12; ++m) {
    float v = 0.f;
    if (m < M) v = X[shdr[H_EJ + m] * 256 + t];
    XeT[t * 12 + m] = v;
  }
  __syncthreads();

  // W pass: pure load+FMA (48 FMA per float4), accumulate Wh@entries
  const float* Wb = Wst + b * 16384;
  int fg = l >> 4, kc = (l & 15) << 2;
  float wh[12][4];
  #pragma unroll
  for (int m = 0; m < 12; ++m) { wh[m][0] = wh[m][1] = wh[m][2] = wh[m][3] = 0.f; }
  #pragma unroll 4
  for (int it = 0; it < 16; ++it) {
    int f = w * 64 + it * 4 + fg;
    float4 wq = *reinterpret_cast<const float4*>(Wb + f * 64 + kc);
    const float4* xr = reinterpret_cast<const float4*>(&XeT[f * 12]);
    float4 xa = xr[0], xb = xr[1], xc = xr[2];
    float xv[12] = { xa.x, xa.y, xa.z, xa.w, xb.x, xb.y, xb.z, xb.w,
                     xc.x, xc.y, xc.z, xc.w };
    #pragma unroll
    for (int m = 0; m < 12; ++m) {
      wh[m][0] += xv[m] * wq.x;
      wh[m][1] += xv[m] * wq.y;
      wh[m][2] += xv[m] * wq.z;
      wh[m][3] += xv[m] * wq.w;
    }
  }
  #pragma unroll
  for (int m = 0; m < 12; ++m) {
    #pragma unroll
    for (int q = 0; q < 4; ++q) {
      float x = wh[m][q];
      x += __shfl_xor(x, 16);
      x += __shfl_xor(x, 32);
      wh[m][q] = x;
    }
  }
  if (l < 16) {
    #pragma unroll
    for (int m = 0; m < 12; ++m) {
      float4 vv = make_float4(wh[m][0], wh[m][1], wh[m][2], wh[m][3]);
      *reinterpret_cast<float4*>(&whp[w * 768 + m * 64 + kc]) = vv;
    }
  }
  __syncthreads();
  #pragma unroll
  for (int c = 0; c < 3; ++c) {
    int o = c * 256 + t;
    whl[o] = whp[o] + whp[768 + o] + whp[1536 + o] + whp[2304 + o];
  }
  // e1 at adjacency rows (w1 precomputed in k1)
  for (int r = w; r < R; r += 4) {
    int row = shdr[H_ROWS + r];
    float p = 0.f;
    #pragma unroll
    for (int s = 0; s < 4; ++s) {
      int f = s * 64 + l;
      p += X[row * 256 + f] * w1l[f];
    }
    #pragma unroll
    for (int d = 1; d < 64; d <<= 1) p += __shfl_xor(p, d);
    if (l == 0) e1r[r] = p;
  }
  __syncthreads();

  // softmax stats
  {
    float p = fmaxf(e2s[w * 128 + l], e2s[w * 128 + 64 + l]);
    #pragma unroll
    for (int d = 1; d < 64; d <<= 1) p = fmaxf(p, __shfl_xor(p, d));
    if (l == 0) redv[w] = p;
  }
  __syncthreads();
  float maxe2 = fmaxf(fmaxf(redv[0], redv[1]), fmaxf(redv[2], redv[3]));
  for (int r = 0; r < R; ++r) {
    float e1_ = e1r[r];
    float m_ = leaky_(e1_ + maxe2);
    float pe = __expf(leaky_(e1_ + e2s[t]) - m_) + __expf(leaky_(e1_ + e2s[t + 256]) - m_);
    #pragma unroll
    for (int d = 1; d < 64; d <<= 1) pe += __shfl_xor(pe, d);
    if (l == 0) redf[r * 4 + w] = pe;
    if (t == r) mr12[r] = m_;
  }
  __syncthreads();
  if (t < R) sr12[t] = redf[t * 4] + redf[t * 4 + 1] + redf[t * 4 + 2] + redf[t * 4 + 3];
  __syncthreads();
  if (t < M) {
    int r = shdr[H_ER + t];
    av12[t] = __expf(leaky_(e1r[r] + e2s[shdr[H_EJ + t]]) - mr12[r]) / sr12[r];
  }
  __syncthreads();
  for (int r = w; r < R; r += 4) {
    float a = 0.f;
    #pragma unroll
    for (int m = 0; m < 12; ++m) {
      if (m < M && shdr[H_ER + m] == r) a += av12[m] * whl[m * 64 + l];
    }
    wsf[MIDC_OFF + r * 32768 + b * 64 + l] = elu_(a);
  }
}

// K4: Wh2 partials: block b covers mid columns [b*256, b*256+256)
__global__ __launch_bounds__(256) void k4_wh2(const float* __restrict__ Wout,
                                              float* __restrict__ wsf) {
  __shared__ __align__(16) float midT[3072];
  __shared__ float whp4[4][768];
  int b = blockIdx.x, t = threadIdx.x, l = t & 63, w = t >> 6;
  const int* ip = (const int*)(wsf + INT_OFF);
  int R = ip[H_R];

  #pragma unroll
  for (int m = 0; m < 12; ++m) {
    float v = 0.f;
    if (m < R) v = wsf[MIDC_OFF + m * 32768 + b * 256 + t];
    midT[t * 12 + m] = v;
  }
  __syncthreads();
  float acc[12];
  #pragma unroll
  for (int m = 0; m < 12; ++m) acc[m] = 0.f;
  #pragma unroll 2
  for (int ci = 0; ci < 64; ++ci) {
    int cc = w * 64 + ci;
    float wv = Wout[(b * 256 + cc) * 64 + l];
    const float4* xr = reinterpret_cast<const float4*>(&midT[cc * 12]);
    float4 xa = xr[0], xb = xr[1], xc = xr[2];
    acc[0] += xa.x * wv; acc[1] += xa.y * wv; acc[2]  += xa.z * wv; acc[3]  += xa.w * wv;
    acc[4] += xb.x * wv; acc[5] += xb.y * wv; acc[6]  += xb.z * wv; acc[7]  += xb.w * wv;
    acc[8] += xc.x * wv; acc[9] += xc.y * wv; acc[10] += xc.z * wv; acc[11] += xc.w * wv;
  }
  #pragma unroll
  for (int m = 0; m < 12; ++m) whp4[w][m * 64 + l] = acc[m];
  __syncthreads();
  #pragma unroll
  for (int c = 0; c < 3; ++c) {
    int o = c * 256 + t;
    float s = whp4[0][o] + whp4[1][o] + whp4[2][o] + whp4[3][o];
    wsf[PART_OFF + b * 768 + o] = s;
  }
}

// K5: reduce Wh2 partials; layer-2 closed-form softmax; final elu(V*elu(out2))
__global__ void k5_final(const float* __restrict__ aout, const float* __restrict__ V,
                         float* __restrict__ wsf, float* __restrict__ out) {
  __shared__ float Wh2[768];
  __shared__ float e1o[12], e2o[12], mr[12], sr[12], avals[12];
  int t = threadIdx.x;
  const int* ip = (const int*)(wsf + INT_OFF);
  int M = ip[H_M], R = ip[H_R];
  for (int o = t, c = 0; c < 3; ++c, o += 256) {
    float s = 0.f;
    #pragma unroll 8
    for (int bb = 0; bb < 128; ++bb) s += wsf[PART_OFF + bb * 768 + o];
    Wh2[o] = s;
  }
  __syncthreads();
  if (t < R) {
    float s1 = 0.f, s2 = 0.f;
    for (int k = 0; k < 64; ++k) {
      float wv = Wh2[t * 64 + k];
      s1 += wv * aout[k];
      s2 += wv * aout[64 + k];
    }
    e1o[t] = s1; e2o[t] = s2;
  }
  __syncthreads();
  if (t < R) {
    float maxe = 0.f;  // includes (512-R) implicit zeros
    for (int r = 0; r < R; ++r) maxe = fmaxf(maxe, e2o[r]);
    float m_ = leaky_(e1o[t] + maxe);
    float s = (float)(512 - R) * __expf(leaky_(e1o[t]) - m_);
    for (int r = 0; r < R; ++r) s += __expf(leaky_(e1o[t] + e2o[r]) - m_);
    mr[t] = m_; sr[t] = s;
  }
  __syncthreads();
  if (t < M) {
    int r = ip[H_ER + t];
    int cj = ip[H_ECJ + t];
    float e2v = (cj >= 0) ? e2o[cj] : 0.f;
    avals[t] = __expf(leaky_(e1o[r] + e2v) - mr[r]) / sr[r];
  }
  __syncthreads();
  int l = t & 63, w = t >> 6;
  for (int r = w; r < R; r += 4) {
    float a = 0.f;
    #pragma unroll
    for (int m = 0; m < 12; ++m) {
      if (m < M && ip[H_ER + m] == r) {
        int cj = ip[H_ECJ + m];
        float wv = (cj >= 0) ? Wh2[cj * 64 + l] : 0.f;
        a += avals[m] * wv;
      }
    }
    int row = ip[H_ROWS + r];
    float o2 = elu_(a);
    out[262144 + row * 64 + l] = elu_(V[row * 64 + l] * o2);
  }
}

extern "C" void kernel_launch(void* const* d_in, const int* in_sizes, int n_in,
                              void* d_out, int out_size, void* d_ws, size_t ws_size,
                              hipStream_t stream) {
  const float* X    = (const float*)d_in[0];
  const float* Wst  = (const float*)d_in[1];
  const float* ast  = (const float*)d_in[2];
  const float* Wout = (const float*)d_in[3];
  const float* aout = (const float*)d_in[4];
  const float* V    = (const float*)d_in[5];
  float* out = (float*)d_out;
  float* wsf = (float*)d_ws;

  k1_prep  <<<1024, 256, 0, stream>>>(V, Wst, ast, wsf, out);
  k2_e2hdr <<<257,  256, 0, stream>>>(X, wsf);
  k3_heads <<<512,  256, 0, stream>>>(X, Wst, wsf, out);
  k4_wh2   <<<128,  256, 0, stream>>>(Wout, wsf);
  k5_final <<<1,    256, 0, stream>>>(aout, V, wsf, out);
}